// Round 5
// baseline (176.485 us; speedup 1.0000x reference)
//
#include <hip/hip_runtime.h>
#include <hip/hip_cooperative_groups.h>

namespace cg = cooperative_groups;

#define B 64
#define L 1024
#define H 768
#define NROWS (B * L)
#define LOG2E 1.4426950408889634f
#define CS 16
#define NCH 64
#define NEG -1e30f

#define EXP2(x) __builtin_amdgcn_exp2f(x)
#define LOG2(x) __builtin_amdgcn_logf(x)

// ---------------- Kernel 1: featsT[l][b][k] = (hidden[b,l,:].w[k,:] + bias[k]) * log2(e)
__global__ __launch_bounds__(256) void feats_kernel(
    const float* __restrict__ hidden, const float* __restrict__ w,
    const float* __restrict__ bias, float4* __restrict__ featsT)
{
    const int lane = threadIdx.x & 63;
    const int wave = (blockIdx.x * blockDim.x + threadIdx.x) >> 6;
    const int nwaves = (gridDim.x * blockDim.x) >> 6;

    float wr[3][4][4];
#pragma unroll
    for (int c = 0; c < 3; ++c)
#pragma unroll
        for (int j = 0; j < 4; ++j)
#pragma unroll
            for (int k = 0; k < 4; ++k)
                wr[c][j][k] = w[k * H + lane * 4 + 256 * c + j];
    const float bb0 = bias[0], bb1 = bias[1], bb2 = bias[2], bb3 = bias[3];

    for (int row = wave; row < NROWS; row += nwaves) {
        const float4* hrow = reinterpret_cast<const float4*>(hidden) + (size_t)row * (H / 4);
        float acc[4] = {0.f, 0.f, 0.f, 0.f};
#pragma unroll
        for (int c = 0; c < 3; ++c) {
            float4 h = hrow[lane + 64 * c];
            const float hv[4] = {h.x, h.y, h.z, h.w};
#pragma unroll
            for (int j = 0; j < 4; ++j)
#pragma unroll
                for (int k = 0; k < 4; ++k)
                    acc[k] = fmaf(hv[j], wr[c][j][k], acc[k]);
        }
#pragma unroll
        for (int k = 0; k < 4; ++k) {
            float v = acc[k];
#pragma unroll
            for (int s = 32; s >= 1; s >>= 1) v += __shfl_xor(v, s, 64);
            acc[k] = v;
        }
        if (lane == 0) {
            const int b = row >> 10, l = row & 1023;
            featsT[l * B + b] = make_float4((acc[0] + bb0) * LOG2E, (acc[1] + bb1) * LOG2E,
                                            (acc[2] + bb2) * LOG2E, (acc[3] + bb3) * LOG2E);
        }
    }
}

// ---------------- Kernel 2 (cooperative): chunkmat -> bound -> rescan+sp -> normalize
__global__ __launch_bounds__(128) void crf_mid_kernel(
    const float4* __restrict__ featsT, const int* __restrict__ seq_lens,
    const float* __restrict__ T, float* __restrict__ mats,
    float* __restrict__ vbound, float* __restrict__ logZ,
    float* __restrict__ spu, float* __restrict__ chunksum,
    float* __restrict__ sprob)
{
    cg::grid_group grid = cg::this_grid();
    const int tid = threadIdx.x;
    const int b = tid & 63;
    const int dir = tid >> 6;
    const int c = blockIdx.x;
    const int sl = seq_lens[b];

    float eT2[4][4];
#pragma unroll
    for (int i = 0; i < 4; ++i)
#pragma unroll
        for (int j = 0; j < 4; ++j) eT2[i][j] = EXP2(T[i * 4 + j] * LOG2E);

    // ===== Phase 1: per-chunk 4x4 transfer matrices =====
    {
        const int lo = c * CS + 1;
        const int hi = min(c * CS + CS, L - 1);
        const int ns = hi - lo + 1;

        float4 fr[CS];
#pragma unroll
        for (int u = 0; u < CS; ++u) {
            const int t = dir ? max(hi - u, lo) : min(lo + u, hi);
            fr[u] = featsT[t * B + b];
        }

        float M[4][4];
#pragma unroll
        for (int i = 0; i < 4; ++i)
#pragma unroll
            for (int j = 0; j < 4; ++j) M[i][j] = (i == j) ? 0.f : NEG;

        if (dir == 0) {
#pragma unroll
            for (int u = 0; u < CS; ++u) {
                const int t = lo + u;
                const bool valid = (u < ns) && (t < sl);
                const float f[4] = {fr[u].x, fr[u].y, fr[u].z, fr[u].w};
                float nM[4][4];
#pragma unroll
                for (int i = 0; i < 4; ++i) {
                    const float rm = fmaxf(fmaxf(M[i][0], M[i][1]), fmaxf(M[i][2], M[i][3]));
                    const float e0 = EXP2(M[i][0] - rm), e1 = EXP2(M[i][1] - rm);
                    const float e2 = EXP2(M[i][2] - rm), e3 = EXP2(M[i][3] - rm);
#pragma unroll
                    for (int j = 0; j < 4; ++j) {
                        const float s = (e0 * eT2[0][j] + e1 * eT2[1][j]) + (e2 * eT2[2][j] + e3 * eT2[3][j]);
                        nM[i][j] = f[j] + rm + LOG2(s);
                    }
                }
#pragma unroll
                for (int i = 0; i < 4; ++i)
#pragma unroll
                    for (int j = 0; j < 4; ++j) M[i][j] = valid ? nM[i][j] : M[i][j];
            }
        } else {
#pragma unroll
            for (int u = 0; u < CS; ++u) {
                const int n = hi - u;
                const bool valid = (u < ns) && (n < sl);
                const float f[4] = {fr[u].x, fr[u].y, fr[u].z, fr[u].w};
                float nM[4][4];
#pragma unroll
                for (int j = 0; j < 4; ++j) {
                    const float c0 = f[0] + M[0][j], c1 = f[1] + M[1][j];
                    const float c2 = f[2] + M[2][j], c3 = f[3] + M[3][j];
                    const float cm = fmaxf(fmaxf(c0, c1), fmaxf(c2, c3));
                    const float g0 = EXP2(c0 - cm), g1 = EXP2(c1 - cm);
                    const float g2 = EXP2(c2 - cm), g3 = EXP2(c3 - cm);
#pragma unroll
                    for (int i = 0; i < 4; ++i) {
                        const float s = (g0 * eT2[i][0] + g1 * eT2[i][1]) + (g2 * eT2[i][2] + g3 * eT2[i][3]);
                        nM[i][j] = cm + LOG2(s);
                    }
                }
#pragma unroll
                for (int i = 0; i < 4; ++i)
#pragma unroll
                    for (int j = 0; j < 4; ++j) M[i][j] = valid ? nM[i][j] : M[i][j];
            }
        }
#pragma unroll
        for (int i = 0; i < 4; ++i)
#pragma unroll
            for (int j = 0; j < 4; ++j)
                mats[((dir * NCH + c) * 16 + i * 4 + j) * B + b] = M[i][j];
    }

    grid.sync();

    // ===== Phase 2: serial scan over chunk matrices (block 0 only) =====
    if (blockIdx.x == 0) {
        float Ms[4][16];
#pragma unroll
        for (int p = 0; p < 3; ++p) {
            const int cc = dir ? (NCH - 1 - p) : p;
#pragma unroll
            for (int k = 0; k < 16; ++k)
                Ms[p][k] = mats[((dir * NCH + cc) * 16 + k) * B + b];
        }

        float v0, v1, v2, v3;
        if (dir == 0) {
            const float4 f0 = featsT[b];
            v0 = f0.x; v1 = f0.y; v2 = f0.z; v3 = f0.w;
        } else {
            v0 = v1 = v2 = v3 = 0.f;
        }

#pragma unroll
        for (int u = 0; u < NCH; ++u) {
            const int cc = dir ? (NCH - 1 - u) : u;
            vbound[((dir * NCH + cc) * 4 + 0) * B + b] = v0;
            vbound[((dir * NCH + cc) * 4 + 1) * B + b] = v1;
            vbound[((dir * NCH + cc) * 4 + 2) * B + b] = v2;
            vbound[((dir * NCH + cc) * 4 + 3) * B + b] = v3;
            if (u + 3 < NCH) {
                const int cp = dir ? (NCH - 1 - (u + 3)) : (u + 3);
#pragma unroll
                for (int k = 0; k < 16; ++k)
                    Ms[(u + 3) & 3][k] = mats[((dir * NCH + cp) * 16 + k) * B + b];
            }
            float n[4];
            if (dir == 0) {
#pragma unroll
                for (int j = 0; j < 4; ++j) {
                    const float c0 = v0 + Ms[u & 3][0 * 4 + j], c1 = v1 + Ms[u & 3][1 * 4 + j];
                    const float c2 = v2 + Ms[u & 3][2 * 4 + j], c3 = v3 + Ms[u & 3][3 * 4 + j];
                    const float m = fmaxf(fmaxf(c0, c1), fmaxf(c2, c3));
                    const float s = (EXP2(c0 - m) + EXP2(c1 - m)) + (EXP2(c2 - m) + EXP2(c3 - m));
                    n[j] = m + LOG2(s);
                }
            } else {
#pragma unroll
                for (int i = 0; i < 4; ++i) {
                    const float c0 = v0 + Ms[u & 3][i * 4 + 0], c1 = v1 + Ms[u & 3][i * 4 + 1];
                    const float c2 = v2 + Ms[u & 3][i * 4 + 2], c3 = v3 + Ms[u & 3][i * 4 + 3];
                    const float m = fmaxf(fmaxf(c0, c1), fmaxf(c2, c3));
                    const float s = (EXP2(c0 - m) + EXP2(c1 - m)) + (EXP2(c2 - m) + EXP2(c3 - m));
                    n[i] = m + LOG2(s);
                }
            }
            v0 = n[0]; v1 = n[1]; v2 = n[2]; v3 = n[3];
        }
        if (dir == 0) {
            const float m = fmaxf(fmaxf(v0, v1), fmaxf(v2, v3));
            logZ[b] = m + LOG2(EXP2(v0 - m) + EXP2(v1 - m) + EXP2(v2 - m) + EXP2(v3 - m));
        }
    }

    grid.sync();

    // ===== Phase 3: rescan chunk [16c..16c+15], sp + chunk sums =====
    __shared__ float ldb[CS * 64];
    {
        const int base = c * CS;

        if (dir == 1) {
            float v0 = vbound[((NCH + c) * 4 + 0) * B + b];
            float v1 = vbound[((NCH + c) * 4 + 1) * B + b];
            float v2 = vbound[((NCH + c) * 4 + 2) * B + b];
            float v3 = vbound[((NCH + c) * 4 + 3) * B + b];
            const bool last = (c == NCH - 1);
            const int hi_n = last ? (L - 1) : (base + CS);
            const int cnt = last ? (CS - 1) : CS;
            if (last) ldb[15 * 64 + b] = v1;
            float4 fr[CS];
#pragma unroll
            for (int u = 0; u < CS; ++u) fr[u] = featsT[max(hi_n - u, base + 1) * B + b];
#pragma unroll
            for (int u = 0; u < CS; ++u) {
                if (u < cnt) {
                    const int n = hi_n - u;
                    const bool valid = n < sl;
                    const float4 f = fr[u];
                    const float c0 = f.x + v0, c1 = f.y + v1, c2 = f.z + v2, c3 = f.w + v3;
                    const float m = fmaxf(fmaxf(c0, c1), fmaxf(c2, c3));
                    const float g0 = EXP2(c0 - m), g1 = EXP2(c1 - m), g2 = EXP2(c2 - m), g3 = EXP2(c3 - m);
                    const float s0 = (g0 * eT2[0][0] + g1 * eT2[0][1]) + (g2 * eT2[0][2] + g3 * eT2[0][3]);
                    const float s1 = (g0 * eT2[1][0] + g1 * eT2[1][1]) + (g2 * eT2[1][2] + g3 * eT2[1][3]);
                    const float s2 = (g0 * eT2[2][0] + g1 * eT2[2][1]) + (g2 * eT2[2][2] + g3 * eT2[2][3]);
                    const float s3 = (g0 * eT2[3][0] + g1 * eT2[3][1]) + (g2 * eT2[3][2] + g3 * eT2[3][3]);
                    const float n0 = m + LOG2(s0), n1 = m + LOG2(s1);
                    const float n2 = m + LOG2(s2), n3 = m + LOG2(s3);
                    v0 = valid ? n0 : v0; v1 = valid ? n1 : v1;
                    v2 = valid ? n2 : v2; v3 = valid ? n3 : v3;
                    ldb[(n - 1 - base) * 64 + b] = v1;
                }
            }
        }

        float av[CS];
        if (dir == 0) {
            float a0 = vbound[(c * 4 + 0) * B + b];
            float a1 = vbound[(c * 4 + 1) * B + b];
            float a2 = vbound[(c * 4 + 2) * B + b];
            float a3 = vbound[(c * 4 + 3) * B + b];
            av[0] = a1;
            float4 fr[CS - 1];
#pragma unroll
            for (int u = 1; u < CS; ++u) fr[u - 1] = featsT[(base + u) * B + b];
#pragma unroll
            for (int u = 1; u < CS; ++u) {
                const int t = base + u;
                const bool valid = t < sl;
                const float4 f = fr[u - 1];
                const float m = fmaxf(fmaxf(a0, a1), fmaxf(a2, a3));
                const float e0 = EXP2(a0 - m), e1 = EXP2(a1 - m), e2 = EXP2(a2 - m), e3 = EXP2(a3 - m);
                const float s0 = (e0 * eT2[0][0] + e1 * eT2[1][0]) + (e2 * eT2[2][0] + e3 * eT2[3][0]);
                const float s1 = (e0 * eT2[0][1] + e1 * eT2[1][1]) + (e2 * eT2[2][1] + e3 * eT2[3][1]);
                const float s2 = (e0 * eT2[0][2] + e1 * eT2[1][2]) + (e2 * eT2[2][2] + e3 * eT2[3][2]);
                const float s3 = (e0 * eT2[0][3] + e1 * eT2[1][3]) + (e2 * eT2[2][3] + e3 * eT2[3][3]);
                const float n0 = f.x + m + LOG2(s0), n1 = f.y + m + LOG2(s1);
                const float n2 = f.z + m + LOG2(s2), n3 = f.w + m + LOG2(s3);
                a0 = valid ? n0 : a0; a1 = valid ? n1 : a1;
                a2 = valid ? n2 : a2; a3 = valid ? n3 : a3;
                av[u] = a1;
            }
        }

        __syncthreads();

        if (dir == 0) {
            const float lz = logZ[b];
            float sp[CS];
            float local = 0.f;
#pragma unroll
            for (int u = 0; u < CS; ++u) {
                const int l = base + u;
                const float x = (l < sl) ? EXP2(av[u] + ldb[u * 64 + b] - lz) : 0.f;
                sp[u] = x;
                local += x;
            }
            float4* dst = reinterpret_cast<float4*>(spu + b * L + base);
#pragma unroll
            for (int q = 0; q < 4; ++q)
                dst[q] = make_float4(sp[4 * q], sp[4 * q + 1], sp[4 * q + 2], sp[4 * q + 3]);
            chunksum[c * 64 + b] = local;
        }
    }

    grid.sync();

    // ===== Phase 4: normalize sprob for batch b2 = blockIdx.x =====
    {
        const int b2 = blockIdx.x;
        __shared__ float s_tot;
        if (tid < 64) {
            float v = chunksum[tid * 64 + b2];
#pragma unroll
            for (int s = 32; s >= 1; s >>= 1) v += __shfl_xor(v, s, 64);
            if (tid == 0) s_tot = v;
        }
        __syncthreads();
        const float inv = 1.0f / (0.5f * s_tot);
        const float4* sv = reinterpret_cast<const float4*>(spu + b2 * L);
        float4* dv = reinterpret_cast<float4*>(sprob + b2 * L);
#pragma unroll
        for (int q = 0; q < 2; ++q) {
            const int i = tid + q * 128;
            const float4 v4 = sv[i];
            dv[i] = make_float4(v4.x * inv, v4.y * inv, v4.z * inv, v4.w * inv);
        }
    }
}

// ---------------- Kernel 3 (cooperative): sent_vs partials -> reduce + scalar
__global__ __launch_bounds__(192) void sentv_final_kernel(
    const float* __restrict__ hidden, const float* __restrict__ spu,
    const float* __restrict__ chunksum, const float* __restrict__ T,
    float* __restrict__ partial, float* __restrict__ out)
{
    cg::grid_group grid = cg::this_grid();
    const int blk = blockIdx.x;      // 0..255
    const int lc = blk & 3;
    const int b = blk >> 2;
    const int tid = threadIdx.x;

    __shared__ float s_inv;
    if (tid < 64) {
        float v = chunksum[tid * 64 + b];
#pragma unroll
        for (int s = 32; s >= 1; s >>= 1) v += __shfl_xor(v, s, 64);
        if (tid == 0) s_inv = 2.0f / v; // 1/gamma
    }
    __syncthreads();
    const float inv = s_inv;

    const float4* hb = reinterpret_cast<const float4*>(hidden + ((size_t)b * L + lc * 256) * H) + tid;
    const float* sp = spu + b * L + lc * 256;

    float4 acc = make_float4(0.f, 0.f, 0.f, 0.f);
#pragma unroll 4
    for (int l0 = 0; l0 < 256; l0 += 4) {
        const float4 s4 = *reinterpret_cast<const float4*>(sp + l0);
        const float4 h0 = hb[(size_t)(l0 + 0) * 192];
        const float4 h1 = hb[(size_t)(l0 + 1) * 192];
        const float4 h2 = hb[(size_t)(l0 + 2) * 192];
        const float4 h3 = hb[(size_t)(l0 + 3) * 192];
        acc.x = fmaf(s4.x, h0.x, acc.x); acc.y = fmaf(s4.x, h0.y, acc.y);
        acc.z = fmaf(s4.x, h0.z, acc.z); acc.w = fmaf(s4.x, h0.w, acc.w);
        acc.x = fmaf(s4.y, h1.x, acc.x); acc.y = fmaf(s4.y, h1.y, acc.y);
        acc.z = fmaf(s4.y, h1.z, acc.z); acc.w = fmaf(s4.y, h1.w, acc.w);
        acc.x = fmaf(s4.z, h2.x, acc.x); acc.y = fmaf(s4.z, h2.y, acc.y);
        acc.z = fmaf(s4.z, h2.z, acc.z); acc.w = fmaf(s4.z, h2.w, acc.w);
        acc.x = fmaf(s4.w, h3.x, acc.x); acc.y = fmaf(s4.w, h3.y, acc.y);
        acc.z = fmaf(s4.w, h3.z, acc.z); acc.w = fmaf(s4.w, h3.w, acc.w);
    }
    acc.x *= inv; acc.y *= inv; acc.z *= inv; acc.w *= inv;
    reinterpret_cast<float4*>(partial)[((size_t)lc * B + b) * 192 + tid] = acc;

    grid.sync();

    // reduce partials: 256 blocks x 192 threads = 49152 = B*H
    const int idx = blk * 192 + tid;
    out[idx] = (partial[idx] + partial[B * H + idx]) +
               (partial[2 * B * H + idx] + partial[3 * B * H + idx]);
    if (idx == 0) {
        const float pena = fmaxf(T[4] - T[0], 0.f) + fmaxf(T[1] - T[5], 0.f);
        // sum_l |s_prob| == 2.0 analytically (sp >= 0, gamma = sum/2)
        out[B * H] = 0.1f * pena + 0.1f * 2.0f;
    }
}

extern "C" void kernel_launch(void* const* d_in, const int* in_sizes, int n_in,
                              void* d_out, int out_size, void* d_ws, size_t ws_size,
                              hipStream_t stream) {
    const float* hidden   = (const float*)d_in[0];
    const int*   seq_lens = (const int*)d_in[4];
    const float* T        = (const float*)d_in[9];
    const float* w        = (const float*)d_in[7];
    const float* bias     = (const float*)d_in[8];

    float* ws = (float*)d_ws;
    float4* featsT   = (float4*)(ws);           // 262144 floats
    float*  mats     = ws + 262144;             // 131072
    float*  vbound   = ws + 393216;             // 32768
    float*  logZ     = ws + 425984;             // 64
    float*  chunksum = ws + 426048;             // 4096
    float*  spu      = ws + 430144;             // 65536
    float*  partial  = ws + 495680;             // 196608

    float* out   = (float*)d_out;
    float* sprob = out + B * H + 1;

    feats_kernel<<<2048, 256, 0, stream>>>(hidden, w, bias, featsT);

    {
        const float4* featsTc = (const float4*)featsT;
        void* args[] = {(void*)&featsTc, (void*)&seq_lens, (void*)&T, (void*)&mats,
                        (void*)&vbound, (void*)&logZ, (void*)&spu, (void*)&chunksum,
                        (void*)&sprob};
        hipLaunchCooperativeKernel(reinterpret_cast<void*>(crf_mid_kernel),
                                   dim3(NCH), dim3(128), args, 0, stream);
    }
    {
        void* args[] = {(void*)&hidden, (void*)&spu, (void*)&chunksum, (void*)&T,
                        (void*)&partial, (void*)&out};
        hipLaunchCooperativeKernel(reinterpret_cast<void*>(sentv_final_kernel),
                                   dim3(256), dim3(192), args, 0, stream);
    }
}

// Round 6
// 107.010 us; speedup vs baseline: 1.6492x; 1.6492x over previous
//
#include <hip/hip_runtime.h>

#define B 64
#define L 1024
#define H 768
#define NROWS (B * L)
#define LOG2E 1.4426950408889634f
#define CS 16
#define NCH 64
#define NEG -1e30f

#define EXP2(x) __builtin_amdgcn_exp2f(x)
#define LOG2(x) __builtin_amdgcn_logf(x)

// Device-scope barrier for co-resident grids (64 blocks << 256 CUs).
// Counter must be zeroed by a prior kernel in the same stream.
__device__ __forceinline__ void gbarrier(unsigned* cnt, unsigned nblk) {
    __syncthreads();
    if (threadIdx.x == 0) {
        __threadfence(); // release all prior writes (device scope)
        __hip_atomic_fetch_add(cnt, 1u, __ATOMIC_ACQ_REL, __HIP_MEMORY_SCOPE_AGENT);
        while (__hip_atomic_load(cnt, __ATOMIC_ACQUIRE, __HIP_MEMORY_SCOPE_AGENT) < nblk)
            __builtin_amdgcn_s_sleep(1);
        __threadfence(); // acquire side
    }
    __syncthreads();
}

// ---------------- Kernel 1: featsT[l][b][k] = (hidden[b,l,:].w[k,:] + bias[k]) * log2(e)
__global__ __launch_bounds__(256) void feats_kernel(
    const float* __restrict__ hidden, const float* __restrict__ w,
    const float* __restrict__ bias, float4* __restrict__ featsT,
    unsigned* __restrict__ counters)
{
    if (blockIdx.x == 0 && threadIdx.x < 4) counters[threadIdx.x] = 0u;

    const int lane = threadIdx.x & 63;
    const int wave = (blockIdx.x * blockDim.x + threadIdx.x) >> 6;
    const int nwaves = (gridDim.x * blockDim.x) >> 6;

    float wr[3][4][4];
#pragma unroll
    for (int c = 0; c < 3; ++c)
#pragma unroll
        for (int j = 0; j < 4; ++j)
#pragma unroll
            for (int k = 0; k < 4; ++k)
                wr[c][j][k] = w[k * H + lane * 4 + 256 * c + j];
    const float bb0 = bias[0], bb1 = bias[1], bb2 = bias[2], bb3 = bias[3];

    for (int row = wave; row < NROWS; row += nwaves) {
        const float4* hrow = reinterpret_cast<const float4*>(hidden) + (size_t)row * (H / 4);
        float acc[4] = {0.f, 0.f, 0.f, 0.f};
#pragma unroll
        for (int c = 0; c < 3; ++c) {
            float4 h = hrow[lane + 64 * c];
            const float hv[4] = {h.x, h.y, h.z, h.w};
#pragma unroll
            for (int j = 0; j < 4; ++j)
#pragma unroll
                for (int k = 0; k < 4; ++k)
                    acc[k] = fmaf(hv[j], wr[c][j][k], acc[k]);
        }
#pragma unroll
        for (int k = 0; k < 4; ++k) {
            float v = acc[k];
#pragma unroll
            for (int s = 32; s >= 1; s >>= 1) v += __shfl_xor(v, s, 64);
            acc[k] = v;
        }
        if (lane == 0) {
            const int b = row >> 10, l = row & 1023;
            featsT[l * B + b] = make_float4((acc[0] + bb0) * LOG2E, (acc[1] + bb1) * LOG2E,
                                            (acc[2] + bb2) * LOG2E, (acc[3] + bb3) * LOG2E);
        }
    }
}

// ---------------- Kernel 2: chunkmat -> [bar] -> bound -> [bar] -> rescan+sp
__global__ __launch_bounds__(128) void crf_mid_kernel(
    const float4* __restrict__ featsT, const int* __restrict__ seq_lens,
    const float* __restrict__ T, float* __restrict__ mats,
    float* __restrict__ vbound, float* __restrict__ logZ,
    float* __restrict__ spu, float* __restrict__ chunksum,
    unsigned* __restrict__ counters)
{
    const int tid = threadIdx.x;
    const int b = tid & 63;
    const int dir = tid >> 6;
    const int c = blockIdx.x;
    const int sl = seq_lens[b];

    float eT2[4][4];
#pragma unroll
    for (int i = 0; i < 4; ++i)
#pragma unroll
        for (int j = 0; j < 4; ++j) eT2[i][j] = EXP2(T[i * 4 + j] * LOG2E);

    // ===== Phase 1: per-chunk 4x4 transfer matrices =====
    {
        const int lo = c * CS + 1;
        const int hi = min(c * CS + CS, L - 1);
        const int ns = hi - lo + 1;

        float4 fr[CS];
#pragma unroll
        for (int u = 0; u < CS; ++u) {
            const int t = dir ? max(hi - u, lo) : min(lo + u, hi);
            fr[u] = featsT[t * B + b];
        }

        float M[4][4];
#pragma unroll
        for (int i = 0; i < 4; ++i)
#pragma unroll
            for (int j = 0; j < 4; ++j) M[i][j] = (i == j) ? 0.f : NEG;

        if (dir == 0) {
#pragma unroll
            for (int u = 0; u < CS; ++u) {
                const int t = lo + u;
                const bool valid = (u < ns) && (t < sl);
                const float f[4] = {fr[u].x, fr[u].y, fr[u].z, fr[u].w};
                float nM[4][4];
#pragma unroll
                for (int i = 0; i < 4; ++i) {
                    const float rm = fmaxf(fmaxf(M[i][0], M[i][1]), fmaxf(M[i][2], M[i][3]));
                    const float e0 = EXP2(M[i][0] - rm), e1 = EXP2(M[i][1] - rm);
                    const float e2 = EXP2(M[i][2] - rm), e3 = EXP2(M[i][3] - rm);
#pragma unroll
                    for (int j = 0; j < 4; ++j) {
                        const float s = (e0 * eT2[0][j] + e1 * eT2[1][j]) + (e2 * eT2[2][j] + e3 * eT2[3][j]);
                        nM[i][j] = f[j] + rm + LOG2(s);
                    }
                }
#pragma unroll
                for (int i = 0; i < 4; ++i)
#pragma unroll
                    for (int j = 0; j < 4; ++j) M[i][j] = valid ? nM[i][j] : M[i][j];
            }
        } else {
#pragma unroll
            for (int u = 0; u < CS; ++u) {
                const int n = hi - u;
                const bool valid = (u < ns) && (n < sl);
                const float f[4] = {fr[u].x, fr[u].y, fr[u].z, fr[u].w};
                float nM[4][4];
#pragma unroll
                for (int j = 0; j < 4; ++j) {
                    const float c0 = f[0] + M[0][j], c1 = f[1] + M[1][j];
                    const float c2 = f[2] + M[2][j], c3 = f[3] + M[3][j];
                    const float cm = fmaxf(fmaxf(c0, c1), fmaxf(c2, c3));
                    const float g0 = EXP2(c0 - cm), g1 = EXP2(c1 - cm);
                    const float g2 = EXP2(c2 - cm), g3 = EXP2(c3 - cm);
#pragma unroll
                    for (int i = 0; i < 4; ++i) {
                        const float s = (g0 * eT2[i][0] + g1 * eT2[i][1]) + (g2 * eT2[i][2] + g3 * eT2[i][3]);
                        nM[i][j] = cm + LOG2(s);
                    }
                }
#pragma unroll
                for (int i = 0; i < 4; ++i)
#pragma unroll
                    for (int j = 0; j < 4; ++j) M[i][j] = valid ? nM[i][j] : M[i][j];
            }
        }
#pragma unroll
        for (int i = 0; i < 4; ++i)
#pragma unroll
            for (int j = 0; j < 4; ++j)
                mats[((dir * NCH + c) * 16 + i * 4 + j) * B + b] = M[i][j];
    }

    gbarrier(&counters[0], NCH);

    // ===== Phase 2: serial scan over chunk matrices (block 0 only) =====
    if (blockIdx.x == 0) {
        float Ms[8][16];
#pragma unroll
        for (int p = 0; p < 7; ++p) {
            const int cc = dir ? (NCH - 1 - p) : p;
#pragma unroll
            for (int k = 0; k < 16; ++k)
                Ms[p][k] = mats[((dir * NCH + cc) * 16 + k) * B + b];
        }

        float v0, v1, v2, v3;
        if (dir == 0) {
            const float4 f0 = featsT[b];
            v0 = f0.x; v1 = f0.y; v2 = f0.z; v3 = f0.w;
        } else {
            v0 = v1 = v2 = v3 = 0.f;
        }

#pragma unroll
        for (int u = 0; u < NCH; ++u) {
            const int cc = dir ? (NCH - 1 - u) : u;
            vbound[((dir * NCH + cc) * 4 + 0) * B + b] = v0;
            vbound[((dir * NCH + cc) * 4 + 1) * B + b] = v1;
            vbound[((dir * NCH + cc) * 4 + 2) * B + b] = v2;
            vbound[((dir * NCH + cc) * 4 + 3) * B + b] = v3;
            if (u + 7 < NCH) {
                const int cp = dir ? (NCH - 1 - (u + 7)) : (u + 7);
#pragma unroll
                for (int k = 0; k < 16; ++k)
                    Ms[(u + 7) & 7][k] = mats[((dir * NCH + cp) * 16 + k) * B + b];
            }
            float n[4];
            if (dir == 0) {
#pragma unroll
                for (int j = 0; j < 4; ++j) {
                    const float c0 = v0 + Ms[u & 7][0 * 4 + j], c1 = v1 + Ms[u & 7][1 * 4 + j];
                    const float c2 = v2 + Ms[u & 7][2 * 4 + j], c3 = v3 + Ms[u & 7][3 * 4 + j];
                    const float m = fmaxf(fmaxf(c0, c1), fmaxf(c2, c3));
                    const float s = (EXP2(c0 - m) + EXP2(c1 - m)) + (EXP2(c2 - m) + EXP2(c3 - m));
                    n[j] = m + LOG2(s);
                }
            } else {
#pragma unroll
                for (int i = 0; i < 4; ++i) {
                    const float c0 = v0 + Ms[u & 7][i * 4 + 0], c1 = v1 + Ms[u & 7][i * 4 + 1];
                    const float c2 = v2 + Ms[u & 7][i * 4 + 2], c3 = v3 + Ms[u & 7][i * 4 + 3];
                    const float m = fmaxf(fmaxf(c0, c1), fmaxf(c2, c3));
                    const float s = (EXP2(c0 - m) + EXP2(c1 - m)) + (EXP2(c2 - m) + EXP2(c3 - m));
                    n[i] = m + LOG2(s);
                }
            }
            v0 = n[0]; v1 = n[1]; v2 = n[2]; v3 = n[3];
        }
        if (dir == 0) {
            const float m = fmaxf(fmaxf(v0, v1), fmaxf(v2, v3));
            logZ[b] = m + LOG2(EXP2(v0 - m) + EXP2(v1 - m) + EXP2(v2 - m) + EXP2(v3 - m));
        }
    }

    gbarrier(&counters[1], NCH);

    // ===== Phase 3: rescan chunk [16c..16c+15], sp + chunk sums =====
    __shared__ float ldb[CS * 64];
    {
        const int base = c * CS;

        if (dir == 1) {
            float v0 = vbound[((NCH + c) * 4 + 0) * B + b];
            float v1 = vbound[((NCH + c) * 4 + 1) * B + b];
            float v2 = vbound[((NCH + c) * 4 + 2) * B + b];
            float v3 = vbound[((NCH + c) * 4 + 3) * B + b];
            const bool last = (c == NCH - 1);
            const int hi_n = last ? (L - 1) : (base + CS);
            const int cnt = last ? (CS - 1) : CS;
            if (last) ldb[15 * 64 + b] = v1;
            float4 fr[CS];
#pragma unroll
            for (int u = 0; u < CS; ++u) fr[u] = featsT[max(hi_n - u, base + 1) * B + b];
#pragma unroll
            for (int u = 0; u < CS; ++u) {
                if (u < cnt) {
                    const int n = hi_n - u;
                    const bool valid = n < sl;
                    const float4 f = fr[u];
                    const float c0 = f.x + v0, c1 = f.y + v1, c2 = f.z + v2, c3 = f.w + v3;
                    const float m = fmaxf(fmaxf(c0, c1), fmaxf(c2, c3));
                    const float g0 = EXP2(c0 - m), g1 = EXP2(c1 - m), g2 = EXP2(c2 - m), g3 = EXP2(c3 - m);
                    const float s0 = (g0 * eT2[0][0] + g1 * eT2[0][1]) + (g2 * eT2[0][2] + g3 * eT2[0][3]);
                    const float s1 = (g0 * eT2[1][0] + g1 * eT2[1][1]) + (g2 * eT2[1][2] + g3 * eT2[1][3]);
                    const float s2 = (g0 * eT2[2][0] + g1 * eT2[2][1]) + (g2 * eT2[2][2] + g3 * eT2[2][3]);
                    const float s3 = (g0 * eT2[3][0] + g1 * eT2[3][1]) + (g2 * eT2[3][2] + g3 * eT2[3][3]);
                    const float n0 = m + LOG2(s0), n1 = m + LOG2(s1);
                    const float n2 = m + LOG2(s2), n3 = m + LOG2(s3);
                    v0 = valid ? n0 : v0; v1 = valid ? n1 : v1;
                    v2 = valid ? n2 : v2; v3 = valid ? n3 : v3;
                    ldb[(n - 1 - base) * 64 + b] = v1;
                }
            }
        }

        float av[CS];
        if (dir == 0) {
            float a0 = vbound[(c * 4 + 0) * B + b];
            float a1 = vbound[(c * 4 + 1) * B + b];
            float a2 = vbound[(c * 4 + 2) * B + b];
            float a3 = vbound[(c * 4 + 3) * B + b];
            av[0] = a1;
            float4 fr[CS - 1];
#pragma unroll
            for (int u = 1; u < CS; ++u) fr[u - 1] = featsT[(c * CS + u) * B + b];
#pragma unroll
            for (int u = 1; u < CS; ++u) {
                const int t = base + u;
                const bool valid = t < sl;
                const float4 f = fr[u - 1];
                const float m = fmaxf(fmaxf(a0, a1), fmaxf(a2, a3));
                const float e0 = EXP2(a0 - m), e1 = EXP2(a1 - m), e2 = EXP2(a2 - m), e3 = EXP2(a3 - m);
                const float s0 = (e0 * eT2[0][0] + e1 * eT2[1][0]) + (e2 * eT2[2][0] + e3 * eT2[3][0]);
                const float s1 = (e0 * eT2[0][1] + e1 * eT2[1][1]) + (e2 * eT2[2][1] + e3 * eT2[3][1]);
                const float s2 = (e0 * eT2[0][2] + e1 * eT2[1][2]) + (e2 * eT2[2][2] + e3 * eT2[3][2]);
                const float s3 = (e0 * eT2[0][3] + e1 * eT2[1][3]) + (e2 * eT2[2][3] + e3 * eT2[3][3]);
                const float n0 = f.x + m + LOG2(s0), n1 = f.y + m + LOG2(s1);
                const float n2 = f.z + m + LOG2(s2), n3 = f.w + m + LOG2(s3);
                a0 = valid ? n0 : a0; a1 = valid ? n1 : a1;
                a2 = valid ? n2 : a2; a3 = valid ? n3 : a3;
                av[u] = a1;
            }
        }

        __syncthreads();

        if (dir == 0) {
            const float lz = logZ[b];
            float sp[CS];
            float local = 0.f;
#pragma unroll
            for (int u = 0; u < CS; ++u) {
                const int l = base + u;
                const float x = (l < sl) ? EXP2(av[u] + ldb[u * 64 + b] - lz) : 0.f;
                sp[u] = x;
                local += x;
            }
            float4* dst = reinterpret_cast<float4*>(spu + b * L + base);
#pragma unroll
            for (int q = 0; q < 4; ++q)
                dst[q] = make_float4(sp[4 * q], sp[4 * q + 1], sp[4 * q + 2], sp[4 * q + 3]);
            chunksum[c * 64 + b] = local;
        }
    }
}

// ---------------- Kernel 3: sent_vs (direct), sprob normalize, scalar
__global__ __launch_bounds__(256) void sentv_kernel(
    const float* __restrict__ hidden, const float* __restrict__ spu,
    const float* __restrict__ chunksum, const float* __restrict__ T,
    float* __restrict__ out, float* __restrict__ sprob)
{
    const int hc = blockIdx.x;   // 0..2
    const int b  = blockIdx.y;   // 0..63
    const int tid = threadIdx.x;
    const int lane = tid & 63;
    const int w = tid >> 6;

    __shared__ float s_tot;
    if (tid < 64) {
        float v = chunksum[tid * 64 + b];
#pragma unroll
        for (int s = 32; s >= 1; s >>= 1) v += __shfl_xor(v, s, 64);
        if (tid == 0) s_tot = v;
    }
    __syncthreads();
    const float inv = 2.0f / s_tot;  // == 1/gamma

    const float4* hb = reinterpret_cast<const float4*>(hidden + ((size_t)b * L) * H + hc * 256) + lane;
    const float* sp = spu + b * L;

    float4 acc = make_float4(0.f, 0.f, 0.f, 0.f);
#pragma unroll 8
    for (int i = 0; i < 256; ++i) {
        const int l = w + 4 * i;
        const float s = sp[l];
        const float4 h = hb[(size_t)l * (H / 4)];
        acc.x = fmaf(s, h.x, acc.x); acc.y = fmaf(s, h.y, acc.y);
        acc.z = fmaf(s, h.z, acc.z); acc.w = fmaf(s, h.w, acc.w);
    }

    __shared__ float4 red[4][64];
    red[w][lane] = acc;
    __syncthreads();
    if (tid < 64) {
        const float4 a0 = red[0][lane], a1 = red[1][lane], a2 = red[2][lane], a3 = red[3][lane];
        float4 r;
        r.x = ((a0.x + a1.x) + (a2.x + a3.x)) * inv;
        r.y = ((a0.y + a1.y) + (a2.y + a3.y)) * inv;
        r.z = ((a0.z + a1.z) + (a2.z + a3.z)) * inv;
        r.w = ((a0.w + a1.w) + (a2.w + a3.w)) * inv;
        reinterpret_cast<float4*>(out + (size_t)b * H + hc * 256)[lane] = r;
    }

    if (hc == 0) {
#pragma unroll
        for (int q = 0; q < 4; ++q) {
            const int l = tid + q * 256;
            sprob[b * L + l] = sp[l] * inv;
        }
        if (b == 0 && tid == 0) {
            const float pena = fmaxf(T[4] - T[0], 0.f) + fmaxf(T[1] - T[5], 0.f);
            // sum_l |s_prob| == 2.0 analytically (sp >= 0, gamma = sum/2)
            out[B * H] = 0.1f * pena + 0.1f * 2.0f;
        }
    }
}

extern "C" void kernel_launch(void* const* d_in, const int* in_sizes, int n_in,
                              void* d_out, int out_size, void* d_ws, size_t ws_size,
                              hipStream_t stream) {
    const float* hidden   = (const float*)d_in[0];
    const int*   seq_lens = (const int*)d_in[4];
    const float* w        = (const float*)d_in[7];
    const float* bias     = (const float*)d_in[8];
    const float* T        = (const float*)d_in[9];

    float* ws = (float*)d_ws;
    float4*   featsT   = (float4*)(ws);         // 262144 floats
    float*    mats     = ws + 262144;           // 131072
    float*    vbound   = ws + 393216;           // 32768
    float*    logZ     = ws + 425984;           // 64
    float*    chunksum = ws + 426048;           // 4096
    float*    spu      = ws + 430144;           // 65536
    unsigned* counters = (unsigned*)(ws + 495680); // 4 slots

    float* out   = (float*)d_out;
    float* sprob = out + B * H + 1;

    feats_kernel<<<2048, 256, 0, stream>>>(hidden, w, bias, featsT, counters);
    crf_mid_kernel<<<NCH, 128, 0, stream>>>((const float4*)featsT, seq_lens, T, mats,
                                            vbound, logZ, spu, chunksum, counters);
    sentv_kernel<<<dim3(3, 64), 256, 0, stream>>>(hidden, spu, chunksum, T, out, sprob);
}